// Round 7
// baseline (177.786 us; speedup 1.0000x reference)
//
#include <hip/hip_runtime.h>
#include <hip/hip_bf16.h>

// Problem constants (B,T,C,H,W,D) from the reference.
constexpr int B_ = 2, T_ = 2048, C_ = 1024, H_ = 16, W_ = 256, D_ = 64;
constexpr int M_ = B_ * T_;            // 4096 rows
constexpr float SCALE_ = 0.125f;       // 1/sqrt(64)

typedef __attribute__((ext_vector_type(8))) short bf16x8;
typedef __attribute__((ext_vector_type(4))) float f32x4;
typedef unsigned short ushort_t;

static __device__ __forceinline__ unsigned short f2bf(float x) {
    __hip_bfloat16 h = __float2bfloat16(x);
    return *reinterpret_cast<unsigned short*>(&h);
}

// ---------------------------------------------------------------------------
// Cast fp32 -> bf16 for x and the four weights. z selects the array.
// ---------------------------------------------------------------------------
__global__ void cast_to_bf16(
    const float* __restrict__ s0, const float* __restrict__ s1,
    const float* __restrict__ s2, const float* __restrict__ s3,
    const float* __restrict__ s4,
    ushort_t* __restrict__ d0, ushort_t* __restrict__ d1,
    ushort_t* __restrict__ d2, ushort_t* __restrict__ d3,
    ushort_t* __restrict__ d4,
    int n0, int n1, int n2, int n3, int n4)
{
    const int z = blockIdx.z;
    const float* s = (z==0)?s0:(z==1)?s1:(z==2)?s2:(z==3)?s3:s4;
    ushort_t* d = (z==0)?d0:(z==1)?d1:(z==2)?d2:(z==3)?d3:d4;
    const int n8 = ((z==0)?n0:(z==1)?n1:(z==2)?n2:(z==3)?n3:n4) >> 3;
    for (int i = blockIdx.x * blockDim.x + threadIdx.x; i < n8;
         i += gridDim.x * blockDim.x) {
        const float4 f0 = *(const float4*)&s[(size_t)i * 8];
        const float4 f1 = *(const float4*)&s[(size_t)i * 8 + 4];
        uint4 o;
        o.x = (unsigned)f2bf(f0.x) | ((unsigned)f2bf(f0.y) << 16);
        o.y = (unsigned)f2bf(f0.z) | ((unsigned)f2bf(f0.w) << 16);
        o.z = (unsigned)f2bf(f1.x) | ((unsigned)f2bf(f1.y) << 16);
        o.w = (unsigned)f2bf(f1.z) | ((unsigned)f2bf(f1.w) << 16);
        *(uint4*)&d[(size_t)i * 8] = o;
    }
}

// ---------------------------------------------------------------------------
// bf16 MFMA GEMM: Y[m,n] = sum_k A[m,k] * Wt[n,k]   (A @ W.T)
// 128x128 tile, BK=32, 4 waves in 2x2, 4x4 frags of mfma_f32_16x16x32_bf16.
// LDS row stride padded 32 -> 40 elem (80 B = 20 banks): frag-read bank
// starts walk {0,20,8,28,16,4,24,12} -> uniform 2-way (free), was 8-way.
// BF16OUT=true -> Y is bf16; false -> fp32.
// ---------------------------------------------------------------------------
constexpr int SROW = 40;   // padded LDS row stride (elements)

template<bool BF16OUT>
__global__ __launch_bounds__(256, 2) void gemm_bf16(
    const ushort_t* __restrict__ A,
    const ushort_t* __restrict__ B0, const ushort_t* __restrict__ B1,
    const ushort_t* __restrict__ B2,
    void* __restrict__ Y0v, void* __restrict__ Y1v, void* __restrict__ Y2v,
    int M, int N, int K)
{
    const ushort_t* Bm = (blockIdx.z == 0) ? B0 : (blockIdx.z == 1) ? B1 : B2;
    void*           Ymv = (blockIdx.z == 0) ? Y0v : (blockIdx.z == 1) ? Y1v : Y2v;

    __shared__ __align__(16) ushort_t As[128 * SROW];   // [row][k] padded
    __shared__ __align__(16) ushort_t Bs[128 * SROW];

    const int tid = threadIdx.x;
    const int lane = tid & 63, wave = tid >> 6;
    const int m0 = blockIdx.y * 128, n0 = blockIdx.x * 128;
    const int wm = (wave >> 1) * 64, wn = (wave & 1) * 64;
    const int row16 = lane & 15, kg = lane >> 4;

    f32x4 acc[4][4] = {};

    // Staging: 16B chunk c (c=0..511): row = c>>2, k-granule = c&3.
    const int c0 = tid, c1 = tid + 256;
    const size_t ar0 = (size_t)(m0 + (c0 >> 2)) * K + (c0 & 3) * 8;
    const size_t ar1 = (size_t)(m0 + (c1 >> 2)) * K + (c1 & 3) * 8;
    const size_t br0 = (size_t)(n0 + (c0 >> 2)) * K + (c0 & 3) * 8;
    const size_t br1 = (size_t)(n0 + (c1 >> 2)) * K + (c1 & 3) * 8;
    const int ls0 = (c0 >> 2) * SROW + (c0 & 3) * 8;
    const int ls1 = (c1 >> 2) * SROW + (c1 & 3) * 8;

    for (int k0 = 0; k0 < K; k0 += 32) {
        const uint4 a0 = *(const uint4*)&A[ar0 + k0];
        const uint4 a1 = *(const uint4*)&A[ar1 + k0];
        const uint4 b0 = *(const uint4*)&Bm[br0 + k0];
        const uint4 b1 = *(const uint4*)&Bm[br1 + k0];
        __syncthreads();                 // prev iteration's ds_reads done
        *(uint4*)&As[ls0] = a0;
        *(uint4*)&As[ls1] = a1;
        *(uint4*)&Bs[ls0] = b0;
        *(uint4*)&Bs[ls1] = b1;
        __syncthreads();                 // tiles ready

        bf16x8 af[4], bfr[4];
#pragma unroll
        for (int f = 0; f < 4; ++f) {
            af[f]  = *(const bf16x8*)&As[(wm + f * 16 + row16) * SROW + kg * 8];
            bfr[f] = *(const bf16x8*)&Bs[(wn + f * 16 + row16) * SROW + kg * 8];
        }
#pragma unroll
        for (int i = 0; i < 4; ++i)
#pragma unroll
            for (int j = 0; j < 4; ++j)
                acc[i][j] = __builtin_amdgcn_mfma_f32_16x16x32_bf16(
                    af[i], bfr[j], acc[i][j], 0, 0, 0);
    }

    const int orow = (lane >> 4) * 4, ocol = lane & 15;
    if constexpr (BF16OUT) {
        ushort_t* Ym = (ushort_t*)Ymv;
#pragma unroll
        for (int i = 0; i < 4; ++i)
#pragma unroll
            for (int j = 0; j < 4; ++j)
#pragma unroll
                for (int r = 0; r < 4; ++r)
                    Ym[(size_t)(m0 + wm + i * 16 + orow + r) * N +
                       n0 + wn + j * 16 + ocol] = f2bf(acc[i][j][r]);
    } else {
        float* Ym = (float*)Ymv;
#pragma unroll
        for (int i = 0; i < 4; ++i)
#pragma unroll
            for (int j = 0; j < 4; ++j)
#pragma unroll
                for (int r = 0; r < 4; ++r)
                    Ym[(size_t)(m0 + wm + i * 16 + orow + r) * N +
                       n0 + wn + j * 16 + ocol] = acc[i][j][r];
    }
}

// ---------------------------------------------------------------------------
// Sliding-window causal attention with bf16 MFMA for QK^T and PV.
// (unchanged from r5 — passed, ~<46 us; re-evaluate after GEMM fix)
// ---------------------------------------------------------------------------
__global__ __launch_bounds__(256, 4) void attn_win(
    const ushort_t* __restrict__ Q, const ushort_t* __restrict__ K,
    const ushort_t* __restrict__ V, ushort_t* __restrict__ O)
{
    const int b = blockIdx.z, h = blockIdx.y;
    const int q0 = blockIdx.x * 64;
    const int tid = threadIdx.x;
    const int lane = tid & 63, w = tid >> 6;
    const int r16 = lane & 15, kg = lane >> 4;

    __shared__ __align__(16) ushort_t Ql[64 * 64];
    __shared__ __align__(16) ushort_t Kl[64 * 64];
    __shared__ __align__(16) ushort_t Vt[64 * 64];
    __shared__ __align__(16) ushort_t Pl[64 * 64];

    const ushort_t* qbase = Q + (size_t)(b * T_) * C_ + h * D_;
    const ushort_t* kbase = K + (size_t)(b * T_) * C_ + h * D_;
    const ushort_t* vbase = V + (size_t)(b * T_) * C_ + h * D_;

    // ---- stage Q (64 rows x 64 d): granule id g: row=g>>3, gc=g&7.
#pragma unroll
    for (int l = 0; l < 2; ++l) {
        const int g = tid + l * 256;
        const int qr = g >> 3, gc = g & 7;
        const uint4 qv = *(const uint4*)&qbase[(size_t)(q0 + qr) * C_ + gc * 8];
        *(uint4*)&Ql[(qr * 8 + (gc ^ (qr & 7))) * 8] = qv;
    }

    const int qrow = w * 16 + r16;          // A-frag row (q) for this lane
    const int qloc_base = w * 16 + (lane >> 4) * 4;  // C/D rows base

    float m_run[4], l_run[4];
    f32x4 oacc[4] = {};                     // O strip: 4 d-frags x 4 rows
#pragma unroll
    for (int r = 0; r < 4; ++r) { m_run[r] = -1e30f; l_run[r] = 0.f; }

    const int kt_lo = (q0 - W_ > 0) ? (q0 - W_) : 0;
    for (int kt = kt_lo; kt <= q0; kt += 64) {
        __syncthreads();   // prior tile's reads done (first iter: Q staged)
        // ---- stage K tile [k][d] (b128) and V tile transposed -> Vt[d][k]
#pragma unroll
        for (int l = 0; l < 2; ++l) {
            const int g = tid + l * 256;
            const int kr = g >> 3, gc = g & 7;
            const uint4 kv = *(const uint4*)&kbase[(size_t)(kt + kr) * C_ + gc * 8];
            *(uint4*)&Kl[(kr * 8 + (gc ^ (kr & 7))) * 8] = kv;
            const uint4 vv = *(const uint4*)&vbase[(size_t)(kt + kr) * C_ + gc * 8];
            const ushort_t* vs = (const ushort_t*)&vv;
#pragma unroll
            for (int dd = 0; dd < 8; ++dd) {
                const int d = gc * 8 + dd;
                Vt[(d * 8 + ((kr >> 3) ^ (d & 7))) * 8 + (kr & 7)] = vs[dd];
            }
        }
        __syncthreads();   // tiles ready

        // ---- S = Q @ K^T : strip 16 q-rows x 64 k-cols, 4 col-frags
        bf16x8 aq0 = *(const bf16x8*)&Ql[(qrow * 8 + ((0 * 4 + kg) ^ (qrow & 7))) * 8];
        bf16x8 aq1 = *(const bf16x8*)&Ql[(qrow * 8 + ((1 * 4 + kg) ^ (qrow & 7))) * 8];
        f32x4 sacc[4] = {};
#pragma unroll
        for (int j = 0; j < 4; ++j) {
            const int krow = j * 16 + r16;
            const bf16x8 b0 = *(const bf16x8*)&Kl[(krow * 8 + ((0 * 4 + kg) ^ (krow & 7))) * 8];
            const bf16x8 b1 = *(const bf16x8*)&Kl[(krow * 8 + ((1 * 4 + kg) ^ (krow & 7))) * 8];
            sacc[j] = __builtin_amdgcn_mfma_f32_16x16x32_bf16(aq0, b0, sacc[j], 0, 0, 0);
            sacc[j] = __builtin_amdgcn_mfma_f32_16x16x32_bf16(aq1, b1, sacc[j], 0, 0, 0);
        }

        // ---- mask + online softmax; rows r: gi = q0 + qloc_base + r
#pragma unroll
        for (int r = 0; r < 4; ++r) {
            const int gi = q0 + qloc_base + r;
            float sv[4];
            bool ok[4];
            float mi = -1e30f;
#pragma unroll
            for (int j = 0; j < 4; ++j) {
                const int gj = kt + j * 16 + r16;
                ok[j] = (gj <= gi) && (gi - gj < W_);
                sv[j] = ok[j] ? sacc[j][r] * SCALE_ : -1e30f;
                mi = fmaxf(mi, sv[j]);
            }
#pragma unroll
            for (int off = 1; off < 16; off <<= 1)
                mi = fmaxf(mi, __shfl_xor(mi, off));

            const float mnew = fmaxf(m_run[r], mi);
            float rsum = 0.f;
            float p[4];
#pragma unroll
            for (int j = 0; j < 4; ++j) {
                p[j] = ok[j] ? __expf(sv[j] - mnew) : 0.f;
                rsum += p[j];
            }
#pragma unroll
            for (int off = 1; off < 16; off <<= 1)
                rsum += __shfl_xor(rsum, off);

            const float fac = __expf(m_run[r] - mnew);
            l_run[r] = l_run[r] * fac + rsum;
            m_run[r] = mnew;
#pragma unroll
            for (int jd = 0; jd < 4; ++jd) oacc[jd][r] *= fac;

            // P -> bf16 -> Pl[q][k] (own strip only; no cross-wave use)
            const int q = qloc_base + r;
#pragma unroll
            for (int j = 0; j < 4; ++j) {
                const int k = j * 16 + r16;
                Pl[(q * 8 + ((k >> 3) ^ (q & 7))) * 8 + (k & 7)] = f2bf(p[j]);
            }
        }

        // ---- O += P @ V : A = Pl strip, B = Vt
        const bf16x8 pa0 = *(const bf16x8*)&Pl[(qrow * 8 + ((0 * 4 + kg) ^ (qrow & 7))) * 8];
        const bf16x8 pa1 = *(const bf16x8*)&Pl[(qrow * 8 + ((1 * 4 + kg) ^ (qrow & 7))) * 8];
#pragma unroll
        for (int jd = 0; jd < 4; ++jd) {
            const int drow = jd * 16 + r16;
            const bf16x8 v0 = *(const bf16x8*)&Vt[(drow * 8 + ((0 * 4 + kg) ^ (drow & 7))) * 8];
            const bf16x8 v1 = *(const bf16x8*)&Vt[(drow * 8 + ((1 * 4 + kg) ^ (drow & 7))) * 8];
            oacc[jd] = __builtin_amdgcn_mfma_f32_16x16x32_bf16(pa0, v0, oacc[jd], 0, 0, 0);
            oacc[jd] = __builtin_amdgcn_mfma_f32_16x16x32_bf16(pa1, v1, oacc[jd], 0, 0, 0);
        }
    }

    // ---- normalize, store bf16: O[(b*T + q0 + qloc + r)][h*64 + jd*16 + col]
    ushort_t* obase = O + (size_t)(b * T_) * C_ + h * D_;
#pragma unroll
    for (int r = 0; r < 4; ++r) {
        const float inv = 1.f / l_run[r];
        const size_t row = (size_t)(q0 + qloc_base + r) * C_;
#pragma unroll
        for (int jd = 0; jd < 4; ++jd)
            obase[row + jd * 16 + r16] = f2bf(oacc[jd][r] * inv);
    }
}

// ---------------------------------------------------------------------------
extern "C" void kernel_launch(void* const* d_in, const int* in_sizes, int n_in,
                              void* d_out, int out_size, void* d_ws, size_t ws_size,
                              hipStream_t stream)
{
    const float* x  = (const float*)d_in[0];
    const float* wq = (const float*)d_in[1];
    const float* wk = (const float*)d_in[2];
    const float* wv = (const float*)d_in[3];
    const float* wo = (const float*)d_in[4];
    float* out = (float*)d_out;

    // Workspace layout (bf16 everywhere; ~40 MB)
    ushort_t* qb  = (ushort_t*)d_ws;                // [M_, C_] bf16
    ushort_t* kb  = qb  + (size_t)M_ * C_;
    ushort_t* vb  = kb  + (size_t)M_ * C_;
    ushort_t* xb  = vb  + (size_t)M_ * C_;          // [M_, C_] bf16
    ushort_t* wqb = xb  + (size_t)M_ * C_;          // [C_, C_] bf16
    ushort_t* wkb = wqb + (size_t)C_ * C_;
    ushort_t* wvb = wkb + (size_t)C_ * C_;
    ushort_t* wob = wvb + (size_t)C_ * C_;
    ushort_t* ab  = xb;   // attention out reuses xb (dead after QKV GEMM)

    // 1. Cast inputs to bf16.
    cast_to_bf16<<<dim3(1024, 1, 5), 256, 0, stream>>>(
        x, wq, wk, wv, wo, xb, wqb, wkb, wvb, wob,
        M_ * C_, C_ * C_, C_ * C_, C_ * C_, C_ * C_);

    // 2. Fused QKV projections (bf16 MFMA, bf16 out).
    gemm_bf16<true><<<dim3(C_ / 128, M_ / 128, 3), 256, 0, stream>>>(
        xb, wqb, wkb, wvb, qb, kb, vb, M_, C_, C_);

    // 3. Windowed attention (MFMA), bf16 out.
    attn_win<<<dim3(T_ / 64, H_, B_), 256, 0, stream>>>(qb, kb, vb, ab);

    // 4. Output projection (bf16 MFMA, fp32 out).
    gemm_bf16<false><<<dim3(C_ / 128, M_ / 128, 1), 256, 0, stream>>>(
        ab, wob, wob, wob, out, out, out, M_, C_, C_);
}

// Round 8
// 165.588 us; speedup vs baseline: 1.0737x; 1.0737x over previous
//
#include <hip/hip_runtime.h>
#include <hip/hip_bf16.h>

// Problem constants (B,T,C,H,W,D) from the reference.
constexpr int B_ = 2, T_ = 2048, C_ = 1024, H_ = 16, W_ = 256, D_ = 64;
constexpr int M_ = B_ * T_;            // 4096 rows
constexpr float SCALE_ = 0.125f;       // 1/sqrt(64)

typedef __attribute__((ext_vector_type(8))) short bf16x8;
typedef __attribute__((ext_vector_type(4))) float f32x4;
typedef unsigned short ushort_t;

static __device__ __forceinline__ unsigned short f2bf(float x) {
    __hip_bfloat16 h = __float2bfloat16(x);
    return *reinterpret_cast<unsigned short*>(&h);
}

// Async global->LDS, 16 B per lane. LDS dest must be wave-uniform base
// (HW: base + lane*16); global src is per-lane. [m97/m193]
static __device__ __forceinline__ void gload_lds16(const ushort_t* gp, ushort_t* lp) {
    __builtin_amdgcn_global_load_lds(
        (const __attribute__((address_space(1))) void*)gp,
        (__attribute__((address_space(3))) void*)lp, 16, 0, 0);
}

// ---------------------------------------------------------------------------
// Cast fp32 -> bf16 for x and the four weights. z selects the array.
// ---------------------------------------------------------------------------
__global__ void cast_to_bf16(
    const float* __restrict__ s0, const float* __restrict__ s1,
    const float* __restrict__ s2, const float* __restrict__ s3,
    const float* __restrict__ s4,
    ushort_t* __restrict__ d0, ushort_t* __restrict__ d1,
    ushort_t* __restrict__ d2, ushort_t* __restrict__ d3,
    ushort_t* __restrict__ d4,
    int n0, int n1, int n2, int n3, int n4)
{
    const int z = blockIdx.z;
    const float* s = (z==0)?s0:(z==1)?s1:(z==2)?s2:(z==3)?s3:s4;
    ushort_t* d = (z==0)?d0:(z==1)?d1:(z==2)?d2:(z==3)?d3:d4;
    const int n8 = ((z==0)?n0:(z==1)?n1:(z==2)?n2:(z==3)?n3:n4) >> 3;
    for (int i = blockIdx.x * blockDim.x + threadIdx.x; i < n8;
         i += gridDim.x * blockDim.x) {
        const float4 f0 = *(const float4*)&s[(size_t)i * 8];
        const float4 f1 = *(const float4*)&s[(size_t)i * 8 + 4];
        uint4 o;
        o.x = (unsigned)f2bf(f0.x) | ((unsigned)f2bf(f0.y) << 16);
        o.y = (unsigned)f2bf(f0.z) | ((unsigned)f2bf(f0.w) << 16);
        o.z = (unsigned)f2bf(f1.x) | ((unsigned)f2bf(f1.y) << 16);
        o.w = (unsigned)f2bf(f1.z) | ((unsigned)f2bf(f1.w) << 16);
        *(uint4*)&d[(size_t)i * 8] = o;
    }
}

// ---------------------------------------------------------------------------
// bf16 MFMA GEMM: Y[m,n] = sum_k A[m,k] * Wt[n,k]   (A @ W.T)
// TM x 128 tile, BK=32, 4 waves (2x2), mfma_f32_16x16x32_bf16.
// global_load_lds width-16 staging into LINEAR [row][k] LDS (stride 32).
// TM=128: FM=4 frags/wave (QKV, 768 blocks); TM=64: FM=2 (o-proj, 512 blocks
// = 2 blocks/CU instead of 1 — occupancy was the o-proj limiter).
// ---------------------------------------------------------------------------
template<int TM, bool BF16OUT>
__global__ __launch_bounds__(256, 2) void gemm_bf16(
    const ushort_t* __restrict__ A,
    const ushort_t* __restrict__ B0, const ushort_t* __restrict__ B1,
    const ushort_t* __restrict__ B2,
    void* __restrict__ Y0v, void* __restrict__ Y1v, void* __restrict__ Y2v,
    int M, int N, int K)
{
    constexpr int FM  = TM / 32;    // M-frags per wave (4 or 2)
    constexpr int NCA = TM / 64;    // A-staging calls per wave (2 or 1)

    const ushort_t* Bm = (blockIdx.z == 0) ? B0 : (blockIdx.z == 1) ? B1 : B2;
    void*           Ymv = (blockIdx.z == 0) ? Y0v : (blockIdx.z == 1) ? Y1v : Y2v;

    __shared__ __align__(16) ushort_t As[TM * 32];    // [row][k] linear
    __shared__ __align__(16) ushort_t Bs[128 * 32];

    const int tid = threadIdx.x;
    const int lane = tid & 63, w = tid >> 6;
    const int m0 = blockIdx.y * TM, n0 = blockIdx.x * 128;
    const int wm = (w >> 1) * (TM / 2), wn = (w & 1) * 64;
    const int row16 = lane & 15, kg = lane >> 4;

    f32x4 acc[FM][4] = {};

    // Staging map: 16B chunk c -> row=c>>2, k-granule=c&3. Each wave stages
    // contiguous 1KB LDS regions (wave-uniform base), lane's data at +lane*16.
    size_t ag[NCA]; int al[NCA];
#pragma unroll
    for (int j = 0; j < NCA; ++j) {
        const int c = w * (64 * NCA) + j * 64 + lane;
        ag[j] = (size_t)(m0 + (c >> 2)) * K + (c & 3) * 8;
        al[j] = (w * (64 * NCA) + j * 64) * 8;          // wave-uniform
    }
    size_t bg[2]; int bl[2];
#pragma unroll
    for (int j = 0; j < 2; ++j) {
        const int c = w * 128 + j * 64 + lane;
        bg[j] = (size_t)(n0 + (c >> 2)) * K + (c & 3) * 8;
        bl[j] = (w * 128 + j * 64) * 8;                 // wave-uniform
    }

    for (int k0 = 0; k0 < K; k0 += 32) {
        __syncthreads();                // prev iteration's ds_reads done
#pragma unroll
        for (int j = 0; j < NCA; ++j)
            gload_lds16(A + ag[j] + k0, &As[al[j]]);
#pragma unroll
        for (int j = 0; j < 2; ++j)
            gload_lds16(Bm + bg[j] + k0, &Bs[bl[j]]);
        __syncthreads();                // drains vmcnt(0): tiles ready

        bf16x8 af[FM], bfr[4];
#pragma unroll
        for (int i = 0; i < FM; ++i)
            af[i] = *(const bf16x8*)&As[(wm + i * 16 + row16) * 32 + kg * 8];
#pragma unroll
        for (int j = 0; j < 4; ++j)
            bfr[j] = *(const bf16x8*)&Bs[(wn + j * 16 + row16) * 32 + kg * 8];
#pragma unroll
        for (int i = 0; i < FM; ++i)
#pragma unroll
            for (int j = 0; j < 4; ++j)
                acc[i][j] = __builtin_amdgcn_mfma_f32_16x16x32_bf16(
                    af[i], bfr[j], acc[i][j], 0, 0, 0);
    }

    const int orow = (lane >> 4) * 4, ocol = lane & 15;
    if constexpr (BF16OUT) {
        ushort_t* Ym = (ushort_t*)Ymv;
#pragma unroll
        for (int i = 0; i < FM; ++i)
#pragma unroll
            for (int j = 0; j < 4; ++j)
#pragma unroll
                for (int r = 0; r < 4; ++r)
                    Ym[(size_t)(m0 + wm + i * 16 + orow + r) * N +
                       n0 + wn + j * 16 + ocol] = f2bf(acc[i][j][r]);
    } else {
        float* Ym = (float*)Ymv;
#pragma unroll
        for (int i = 0; i < FM; ++i)
#pragma unroll
            for (int j = 0; j < 4; ++j)
#pragma unroll
                for (int r = 0; r < 4; ++r)
                    Ym[(size_t)(m0 + wm + i * 16 + orow + r) * N +
                       n0 + wn + j * 16 + ocol] = acc[i][j][r];
    }
}

// ---------------------------------------------------------------------------
// Sliding-window causal attention with bf16 MFMA for QK^T and PV.
// (unchanged from r5/r6 — passed; becomes next round's optimization target)
// ---------------------------------------------------------------------------
__global__ __launch_bounds__(256, 4) void attn_win(
    const ushort_t* __restrict__ Q, const ushort_t* __restrict__ K,
    const ushort_t* __restrict__ V, ushort_t* __restrict__ O)
{
    const int b = blockIdx.z, h = blockIdx.y;
    const int q0 = blockIdx.x * 64;
    const int tid = threadIdx.x;
    const int lane = tid & 63, w = tid >> 6;
    const int r16 = lane & 15, kg = lane >> 4;

    __shared__ __align__(16) ushort_t Ql[64 * 64];
    __shared__ __align__(16) ushort_t Kl[64 * 64];
    __shared__ __align__(16) ushort_t Vt[64 * 64];
    __shared__ __align__(16) ushort_t Pl[64 * 64];

    const ushort_t* qbase = Q + (size_t)(b * T_) * C_ + h * D_;
    const ushort_t* kbase = K + (size_t)(b * T_) * C_ + h * D_;
    const ushort_t* vbase = V + (size_t)(b * T_) * C_ + h * D_;

    // ---- stage Q (64 rows x 64 d): granule id g: row=g>>3, gc=g&7.
#pragma unroll
    for (int l = 0; l < 2; ++l) {
        const int g = tid + l * 256;
        const int qr = g >> 3, gc = g & 7;
        const uint4 qv = *(const uint4*)&qbase[(size_t)(q0 + qr) * C_ + gc * 8];
        *(uint4*)&Ql[(qr * 8 + (gc ^ (qr & 7))) * 8] = qv;
    }

    const int qrow = w * 16 + r16;          // A-frag row (q) for this lane
    const int qloc_base = w * 16 + (lane >> 4) * 4;  // C/D rows base

    float m_run[4], l_run[4];
    f32x4 oacc[4] = {};                     // O strip: 4 d-frags x 4 rows
#pragma unroll
    for (int r = 0; r < 4; ++r) { m_run[r] = -1e30f; l_run[r] = 0.f; }

    const int kt_lo = (q0 - W_ > 0) ? (q0 - W_) : 0;
    for (int kt = kt_lo; kt <= q0; kt += 64) {
        __syncthreads();   // prior tile's reads done (first iter: Q staged)
        // ---- stage K tile [k][d] (b128) and V tile transposed -> Vt[d][k]
#pragma unroll
        for (int l = 0; l < 2; ++l) {
            const int g = tid + l * 256;
            const int kr = g >> 3, gc = g & 7;
            const uint4 kv = *(const uint4*)&kbase[(size_t)(kt + kr) * C_ + gc * 8];
            *(uint4*)&Kl[(kr * 8 + (gc ^ (kr & 7))) * 8] = kv;
            const uint4 vv = *(const uint4*)&vbase[(size_t)(kt + kr) * C_ + gc * 8];
            const ushort_t* vs = (const ushort_t*)&vv;
#pragma unroll
            for (int dd = 0; dd < 8; ++dd) {
                const int d = gc * 8 + dd;
                Vt[(d * 8 + ((kr >> 3) ^ (d & 7))) * 8 + (kr & 7)] = vs[dd];
            }
        }
        __syncthreads();   // tiles ready

        // ---- S = Q @ K^T : strip 16 q-rows x 64 k-cols, 4 col-frags
        bf16x8 aq0 = *(const bf16x8*)&Ql[(qrow * 8 + ((0 * 4 + kg) ^ (qrow & 7))) * 8];
        bf16x8 aq1 = *(const bf16x8*)&Ql[(qrow * 8 + ((1 * 4 + kg) ^ (qrow & 7))) * 8];
        f32x4 sacc[4] = {};
#pragma unroll
        for (int j = 0; j < 4; ++j) {
            const int krow = j * 16 + r16;
            const bf16x8 b0 = *(const bf16x8*)&Kl[(krow * 8 + ((0 * 4 + kg) ^ (krow & 7))) * 8];
            const bf16x8 b1 = *(const bf16x8*)&Kl[(krow * 8 + ((1 * 4 + kg) ^ (krow & 7))) * 8];
            sacc[j] = __builtin_amdgcn_mfma_f32_16x16x32_bf16(aq0, b0, sacc[j], 0, 0, 0);
            sacc[j] = __builtin_amdgcn_mfma_f32_16x16x32_bf16(aq1, b1, sacc[j], 0, 0, 0);
        }

        // ---- mask + online softmax; rows r: gi = q0 + qloc_base + r
#pragma unroll
        for (int r = 0; r < 4; ++r) {
            const int gi = q0 + qloc_base + r;
            float sv[4];
            bool ok[4];
            float mi = -1e30f;
#pragma unroll
            for (int j = 0; j < 4; ++j) {
                const int gj = kt + j * 16 + r16;
                ok[j] = (gj <= gi) && (gi - gj < W_);
                sv[j] = ok[j] ? sacc[j][r] * SCALE_ : -1e30f;
                mi = fmaxf(mi, sv[j]);
            }
#pragma unroll
            for (int off = 1; off < 16; off <<= 1)
                mi = fmaxf(mi, __shfl_xor(mi, off));

            const float mnew = fmaxf(m_run[r], mi);
            float rsum = 0.f;
            float p[4];
#pragma unroll
            for (int j = 0; j < 4; ++j) {
                p[j] = ok[j] ? __expf(sv[j] - mnew) : 0.f;
                rsum += p[j];
            }
#pragma unroll
            for (int off = 1; off < 16; off <<= 1)
                rsum += __shfl_xor(rsum, off);

            const float fac = __expf(m_run[r] - mnew);
            l_run[r] = l_run[r] * fac + rsum;
            m_run[r] = mnew;
#pragma unroll
            for (int jd = 0; jd < 4; ++jd) oacc[jd][r] *= fac;

            // P -> bf16 -> Pl[q][k] (own strip only; no cross-wave use)
            const int q = qloc_base + r;
#pragma unroll
            for (int j = 0; j < 4; ++j) {
                const int k = j * 16 + r16;
                Pl[(q * 8 + ((k >> 3) ^ (q & 7))) * 8 + (k & 7)] = f2bf(p[j]);
            }
        }

        // ---- O += P @ V : A = Pl strip, B = Vt
        const bf16x8 pa0 = *(const bf16x8*)&Pl[(qrow * 8 + ((0 * 4 + kg) ^ (qrow & 7))) * 8];
        const bf16x8 pa1 = *(const bf16x8*)&Pl[(qrow * 8 + ((1 * 4 + kg) ^ (qrow & 7))) * 8];
#pragma unroll
        for (int jd = 0; jd < 4; ++jd) {
            const int drow = jd * 16 + r16;
            const bf16x8 v0 = *(const bf16x8*)&Vt[(drow * 8 + ((0 * 4 + kg) ^ (drow & 7))) * 8];
            const bf16x8 v1 = *(const bf16x8*)&Vt[(drow * 8 + ((1 * 4 + kg) ^ (drow & 7))) * 8];
            oacc[jd] = __builtin_amdgcn_mfma_f32_16x16x32_bf16(pa0, v0, oacc[jd], 0, 0, 0);
            oacc[jd] = __builtin_amdgcn_mfma_f32_16x16x32_bf16(pa1, v1, oacc[jd], 0, 0, 0);
        }
    }

    // ---- normalize, store bf16: O[(b*T + q0 + qloc + r)][h*64 + jd*16 + col]
    ushort_t* obase = O + (size_t)(b * T_) * C_ + h * D_;
#pragma unroll
    for (int r = 0; r < 4; ++r) {
        const float inv = 1.f / l_run[r];
        const size_t row = (size_t)(q0 + qloc_base + r) * C_;
#pragma unroll
        for (int jd = 0; jd < 4; ++jd)
            obase[row + jd * 16 + r16] = f2bf(oacc[jd][r] * inv);
    }
}

// ---------------------------------------------------------------------------
extern "C" void kernel_launch(void* const* d_in, const int* in_sizes, int n_in,
                              void* d_out, int out_size, void* d_ws, size_t ws_size,
                              hipStream_t stream)
{
    const float* x  = (const float*)d_in[0];
    const float* wq = (const float*)d_in[1];
    const float* wk = (const float*)d_in[2];
    const float* wv = (const float*)d_in[3];
    const float* wo = (const float*)d_in[4];
    float* out = (float*)d_out;

    // Workspace layout (bf16 everywhere; ~40 MB)
    ushort_t* qb  = (ushort_t*)d_ws;                // [M_, C_] bf16
    ushort_t* kb  = qb  + (size_t)M_ * C_;
    ushort_t* vb  = kb  + (size_t)M_ * C_;
    ushort_t* xb  = vb  + (size_t)M_ * C_;          // [M_, C_] bf16
    ushort_t* wqb = xb  + (size_t)M_ * C_;          // [C_, C_] bf16
    ushort_t* wkb = wqb + (size_t)C_ * C_;
    ushort_t* wvb = wkb + (size_t)C_ * C_;
    ushort_t* wob = wvb + (size_t)C_ * C_;
    ushort_t* ab  = xb;   // attention out reuses xb (dead after QKV GEMM)

    // 1. Cast inputs to bf16.
    cast_to_bf16<<<dim3(1024, 1, 5), 256, 0, stream>>>(
        x, wq, wk, wv, wo, xb, wqb, wkb, wvb, wob,
        M_ * C_, C_ * C_, C_ * C_, C_ * C_, C_ * C_);

    // 2. Fused QKV projections (bf16 MFMA, bf16 out), 128x128 tiles.
    gemm_bf16<128, true><<<dim3(C_ / 128, M_ / 128, 3), 256, 0, stream>>>(
        xb, wqb, wkb, wvb, qb, kb, vb, M_, C_, C_);

    // 3. Windowed attention (MFMA), bf16 out.
    attn_win<<<dim3(T_ / 64, H_, B_), 256, 0, stream>>>(qb, kb, vb, ab);

    // 4. Output projection (bf16 MFMA, fp32 out), 64x128 tiles (2 blocks/CU).
    gemm_bf16<64, false><<<dim3(C_ / 128, M_ / 64, 1), 256, 0, stream>>>(
        ab, wob, wob, wob, out, out, out, M_, C_, C_);
}